// Round 1
// baseline (1288.000 us; speedup 1.0000x reference)
//
#include <hip/hip_runtime.h>
#include <hip/hip_bf16.h>
#include <cstdint>
#include <cstddef>

#define CDIM 128
#define NCELLS 100000

typedef __attribute__((ext_vector_type(8))) short short8;
typedef __attribute__((ext_vector_type(4))) float f32x4;

__device__ __forceinline__ unsigned short f2bf(float f) {
    unsigned u = __float_as_uint(f);
    unsigned r = u + 0x7FFFu + ((u >> 16) & 1u);
    return (unsigned short)(r >> 16);
}
__device__ __forceinline__ float sigf(float x) { return 1.f / (1.f + __expf(-x)); }
__device__ __forceinline__ float siluf(float x) { return x * sigf(x); }

// ---------------------------------------------------------------------------
// Weight prep: convert fp32 (fin x 128) matrices to bf16, pre-swizzled into
// MFMA B-fragment order: frag f = ct*ktc + kt holds, for lane l, the 8 bf16
// W[kt*32 + (l>>4)*8 + i][ct*16 + (l&15)], stored contiguously (16B/lane).
// ---------------------------------------------------------------------------
struct PrepArgs {
    const float* src[14];
    int dstoff[14];   // in ushort units
    int fin[14];
    int ktc[14];
    int tend[14];     // cumulative tile counts
};

__global__ void prep_kernel(PrepArgs pa, unsigned short* __restrict__ wb) {
    int tile = blockIdx.x;
    int m = 0;
    while (tile >= pa.tend[m]) m++;
    int local = tile - (m == 0 ? 0 : pa.tend[m - 1]);
    int ktc = pa.ktc[m];
    int ct = local / ktc;
    int kt = local % ktc;
    int l = threadIdx.x;   // 64 threads
    unsigned short* dst = wb + pa.dstoff[m] + (size_t)local * 512 + l * 8;
    const float* src = pa.src[m];
    int fin = pa.fin[m];
    int col = ct * 16 + (l & 15);
#pragma unroll
    for (int i = 0; i < 8; i++) {
        int k = kt * 32 + (l >> 4) * 8 + i;
        float v = (k < fin) ? src[(size_t)k * CDIM + col] : 0.f;
        dst[i] = f2bf(v);
    }
}

// ---------------------------------------------------------------------------
// EConv: per block, 64 edges. Gather [x_s | x_t | inv] -> bf16 LDS A-tile,
// 2-layer MFMA MLP, sigmoid gate, atomic scatter-add into acc[recv].
// ---------------------------------------------------------------------------
template <int NINV>
__global__ __launch_bounds__(256, 2)
void econv_kernel(const float* __restrict__ xs, const float* __restrict__ xt,
                  const int* __restrict__ send, const int* __restrict__ recv,
                  const float* __restrict__ inv,
                  const unsigned short* __restrict__ W1T, const float* __restrict__ b1,
                  const unsigned short* __restrict__ W2T, const float* __restrict__ b2,
                  const float* __restrict__ Wg, const float* __restrict__ bg,
                  float* __restrict__ acc, int E)
{
    constexpr int KT1 = 9;    // K padded to 288
    constexpr int AS  = 296;  // A-tile row stride (bf16), pad vs 288 for banks
    constexpr int YS  = 136;  // Y-tile row stride
    __shared__ unsigned short Alds[64 * AS];
    __shared__ unsigned short Ylds[64 * YS];
    __shared__ float gpart[64];
    __shared__ int   recvl[64];

    const int t  = threadIdx.x;
    const int e0 = blockIdx.x * 64;

    // ---- gather phase: 4 threads per edge, 32 channels each ----
    {
        const int el = t >> 2, q = t & 3;
        const int e  = e0 + el;
        const bool ev = (e < E);
        int si = 0, ri = 0;
        if (ev) { si = send[e]; ri = recv[e]; }
        if (q == 0) { recvl[el] = ri; gpart[el] = 0.f; }
        unsigned short* arow = Alds + el * AS;
        const float* sp = xs + (size_t)si * CDIM + q * 32;
        const float* tp = xt + (size_t)ri * CDIM + q * 32;
#pragma unroll
        for (int i = 0; i < 8; i++) {
            float4 v = ev ? *(const float4*)(sp + i * 4) : make_float4(0.f, 0.f, 0.f, 0.f);
            uint2 o;
            o.x = (unsigned)f2bf(v.x) | ((unsigned)f2bf(v.y) << 16);
            o.y = (unsigned)f2bf(v.z) | ((unsigned)f2bf(v.w) << 16);
            *(uint2*)(arow + q * 32 + i * 4) = o;
        }
#pragma unroll
        for (int i = 0; i < 8; i++) {
            float4 v = ev ? *(const float4*)(tp + i * 4) : make_float4(0.f, 0.f, 0.f, 0.f);
            uint2 o;
            o.x = (unsigned)f2bf(v.x) | ((unsigned)f2bf(v.y) << 16);
            o.y = (unsigned)f2bf(v.z) | ((unsigned)f2bf(v.w) << 16);
            *(uint2*)(arow + 128 + q * 32 + i * 4) = o;
        }
        if (q == 0) {
#pragma unroll
            for (int j = 0; j < NINV; j++)
                arow[256 + j] = f2bf(ev ? inv[(size_t)e * NINV + j] : 0.f);
            for (int j = NINV; j < 32; j++) arow[256 + j] = 0;
        }
    }
    __syncthreads();

    const int wave = t >> 6, lane = t & 63;
    const int wr = (wave & 1) * 32;     // wave row base (edges)
    const int wc = (wave >> 1) * 64;    // wave col base (channels)
    const int lr = lane & 15, lg = lane >> 4;

    // ---- layer 1: A(64x288) @ W1(288x128) ----
    f32x4 a1[2][4];
#pragma unroll
    for (int mt = 0; mt < 2; mt++)
#pragma unroll
        for (int ct = 0; ct < 4; ct++) a1[mt][ct] = (f32x4){0.f, 0.f, 0.f, 0.f};

    for (int kt = 0; kt < KT1; ++kt) {
        short8 av[2];
#pragma unroll
        for (int mt = 0; mt < 2; mt++)
            av[mt] = *(const short8*)(Alds + (wr + mt * 16 + lr) * AS + kt * 32 + lg * 8);
#pragma unroll
        for (int ct = 0; ct < 4; ct++) {
            const int cg = (wc >> 4) + ct;
            short8 bv = *(const short8*)(W1T + ((size_t)(cg * KT1 + kt) * 64 + lane) * 8);
            a1[0][ct] = __builtin_amdgcn_mfma_f32_16x16x32_bf16(av[0], bv, a1[0][ct], 0, 0, 0);
            a1[1][ct] = __builtin_amdgcn_mfma_f32_16x16x32_bf16(av[1], bv, a1[1][ct], 0, 0, 0);
        }
    }
    // silu(y1 + b1) -> Ylds (bf16)
#pragma unroll
    for (int ct = 0; ct < 4; ct++) {
        const int col = wc + ct * 16 + lr;
        const float bb = b1[col];
#pragma unroll
        for (int mt = 0; mt < 2; mt++)
#pragma unroll
            for (int j = 0; j < 4; j++) {
                const int row = wr + mt * 16 + lg * 4 + j;
                Ylds[row * YS + col] = f2bf(siluf(a1[mt][ct][j] + bb));
            }
    }
    __syncthreads();

    // ---- layer 2: Y(64x128) @ W2(128x128) ----
    f32x4 a2[2][4];
#pragma unroll
    for (int mt = 0; mt < 2; mt++)
#pragma unroll
        for (int ct = 0; ct < 4; ct++) a2[mt][ct] = (f32x4){0.f, 0.f, 0.f, 0.f};

    for (int kt = 0; kt < 4; ++kt) {
        short8 av[2];
#pragma unroll
        for (int mt = 0; mt < 2; mt++)
            av[mt] = *(const short8*)(Ylds + (wr + mt * 16 + lr) * YS + kt * 32 + lg * 8);
#pragma unroll
        for (int ct = 0; ct < 4; ct++) {
            const int cg = (wc >> 4) + ct;
            short8 bv = *(const short8*)(W2T + ((size_t)(cg * 4 + kt) * 64 + lane) * 8);
            a2[0][ct] = __builtin_amdgcn_mfma_f32_16x16x32_bf16(av[0], bv, a2[0][ct], 0, 0, 0);
            a2[1][ct] = __builtin_amdgcn_mfma_f32_16x16x32_bf16(av[1], bv, a2[1][ct], 0, 0, 0);
        }
    }

    // m = silu(y2 + b2); gate partials
    float wg[4], b2c[4];
#pragma unroll
    for (int ct = 0; ct < 4; ct++) {
        const int col = wc + ct * 16 + lr;
        wg[ct]  = Wg[col];
        b2c[ct] = b2[col];
    }
#pragma unroll
    for (int mt = 0; mt < 2; mt++)
#pragma unroll
        for (int ct = 0; ct < 4; ct++)
#pragma unroll
            for (int j = 0; j < 4; j++)
                a2[mt][ct][j] = siluf(a2[mt][ct][j] + b2c[ct]);

#pragma unroll
    for (int mt = 0; mt < 2; mt++)
#pragma unroll
        for (int j = 0; j < 4; j++) {
            float p = a2[mt][0][j] * wg[0] + a2[mt][1][j] * wg[1] +
                      a2[mt][2][j] * wg[2] + a2[mt][3][j] * wg[3];
            p += __shfl_xor(p, 1, 16);
            p += __shfl_xor(p, 2, 16);
            p += __shfl_xor(p, 4, 16);
            p += __shfl_xor(p, 8, 16);
            if (lr == 0) atomicAdd(&gpart[wr + mt * 16 + lg * 4 + j], p);
        }
    __syncthreads();

    // ---- gated scatter ----
    const float bgs = bg[0];
#pragma unroll
    for (int mt = 0; mt < 2; mt++)
#pragma unroll
        for (int j = 0; j < 4; j++) {
            const int row = wr + mt * 16 + lg * 4 + j;
            if (e0 + row < E) {
                const float g = sigf(gpart[row] + bgs);
                float* base = acc + (size_t)recvl[row] * CDIM;
#pragma unroll
                for (int ct = 0; ct < 4; ct++)
                    atomicAdd(base + wc + ct * 16 + lr, a2[mt][ct][j] * g);
            }
        }
}

// ---------------------------------------------------------------------------
// Update MLP: out = f + silu([f | silu(s1) | silu(s2)] @ W1 + b1) @ W2 + b2
// ---------------------------------------------------------------------------
template <int F>
__global__ __launch_bounds__(256, 2)
void update_kernel(const float* __restrict__ f, const float* __restrict__ s1,
                   const float* __restrict__ s2,
                   const unsigned short* __restrict__ W1T, const float* __restrict__ b1,
                   const unsigned short* __restrict__ W2T, const float* __restrict__ b2,
                   float* __restrict__ out)
{
    constexpr int K   = F * CDIM;
    constexpr int KT1 = K / 32;
    constexpr int AS  = K + 8;
    constexpr int YS  = 136;
    __shared__ unsigned short Alds[64 * AS];
    __shared__ unsigned short Ylds[64 * YS];

    const int t  = threadIdx.x;
    const int n0 = blockIdx.x * 64;
    {
        const int rl = t >> 2, q = t & 3;
        const int n  = n0 + rl;
        const bool nv = (n < NCELLS);
        unsigned short* arow = Alds + rl * AS;
        const float* srcs[3] = {f, s1, s2};
#pragma unroll
        for (int p = 0; p < F; p++) {
            const float* sp = srcs[p] + (size_t)n * CDIM + q * 32;
#pragma unroll
            for (int i = 0; i < 8; i++) {
                float4 v = nv ? *(const float4*)(sp + i * 4) : make_float4(0.f, 0.f, 0.f, 0.f);
                if (p > 0) { v.x = siluf(v.x); v.y = siluf(v.y); v.z = siluf(v.z); v.w = siluf(v.w); }
                uint2 o;
                o.x = (unsigned)f2bf(v.x) | ((unsigned)f2bf(v.y) << 16);
                o.y = (unsigned)f2bf(v.z) | ((unsigned)f2bf(v.w) << 16);
                *(uint2*)(arow + p * CDIM + q * 32 + i * 4) = o;
            }
        }
    }
    __syncthreads();

    const int wave = t >> 6, lane = t & 63;
    const int wr = (wave & 1) * 32;
    const int wc = (wave >> 1) * 64;
    const int lr = lane & 15, lg = lane >> 4;

    f32x4 a1[2][4];
#pragma unroll
    for (int mt = 0; mt < 2; mt++)
#pragma unroll
        for (int ct = 0; ct < 4; ct++) a1[mt][ct] = (f32x4){0.f, 0.f, 0.f, 0.f};

    for (int kt = 0; kt < KT1; ++kt) {
        short8 av[2];
#pragma unroll
        for (int mt = 0; mt < 2; mt++)
            av[mt] = *(const short8*)(Alds + (wr + mt * 16 + lr) * AS + kt * 32 + lg * 8);
#pragma unroll
        for (int ct = 0; ct < 4; ct++) {
            const int cg = (wc >> 4) + ct;
            short8 bv = *(const short8*)(W1T + ((size_t)(cg * KT1 + kt) * 64 + lane) * 8);
            a1[0][ct] = __builtin_amdgcn_mfma_f32_16x16x32_bf16(av[0], bv, a1[0][ct], 0, 0, 0);
            a1[1][ct] = __builtin_amdgcn_mfma_f32_16x16x32_bf16(av[1], bv, a1[1][ct], 0, 0, 0);
        }
    }
#pragma unroll
    for (int ct = 0; ct < 4; ct++) {
        const int col = wc + ct * 16 + lr;
        const float bb = b1[col];
#pragma unroll
        for (int mt = 0; mt < 2; mt++)
#pragma unroll
            for (int j = 0; j < 4; j++) {
                const int row = wr + mt * 16 + lg * 4 + j;
                Ylds[row * YS + col] = f2bf(siluf(a1[mt][ct][j] + bb));
            }
    }
    __syncthreads();

    f32x4 a2[2][4];
#pragma unroll
    for (int mt = 0; mt < 2; mt++)
#pragma unroll
        for (int ct = 0; ct < 4; ct++) a2[mt][ct] = (f32x4){0.f, 0.f, 0.f, 0.f};

    for (int kt = 0; kt < 4; ++kt) {
        short8 av[2];
#pragma unroll
        for (int mt = 0; mt < 2; mt++)
            av[mt] = *(const short8*)(Ylds + (wr + mt * 16 + lr) * YS + kt * 32 + lg * 8);
#pragma unroll
        for (int ct = 0; ct < 4; ct++) {
            const int cg = (wc >> 4) + ct;
            short8 bv = *(const short8*)(W2T + ((size_t)(cg * 4 + kt) * 64 + lane) * 8);
            a2[0][ct] = __builtin_amdgcn_mfma_f32_16x16x32_bf16(av[0], bv, a2[0][ct], 0, 0, 0);
            a2[1][ct] = __builtin_amdgcn_mfma_f32_16x16x32_bf16(av[1], bv, a2[1][ct], 0, 0, 0);
        }
    }

    float b2c[4];
#pragma unroll
    for (int ct = 0; ct < 4; ct++) b2c[ct] = b2[wc + ct * 16 + lr];

#pragma unroll
    for (int mt = 0; mt < 2; mt++)
#pragma unroll
        for (int j = 0; j < 4; j++) {
            const int row = wr + mt * 16 + lg * 4 + j;
            const int n2  = n0 + row;
            if (n2 < NCELLS) {
#pragma unroll
                for (int ct = 0; ct < 4; ct++) {
                    const int col = wc + ct * 16 + lr;
                    out[(size_t)n2 * CDIM + col] =
                        f[(size_t)n2 * CDIM + col] + a2[mt][ct][j] + b2c[ct];
                }
            }
        }
}

// ---------------------------------------------------------------------------
extern "C" void kernel_launch(void* const* d_in, const int* in_sizes, int n_in,
                              void* d_out, int out_size, void* d_ws, size_t ws_size,
                              hipStream_t stream)
{
    const float* f0 = (const float*)d_in[0];
    const float* f1 = (const float*)d_in[1];
    const float* f2 = (const float*)d_in[2];

    // relation input blocks: send,recv,inv,W1,b1,W2,b2,Wg,bg
    const int*   a0_send = (const int*)d_in[3];
    const int*   a0_recv = (const int*)d_in[4];
    const float* inv_a0  = (const float*)d_in[5];
    const float* a0_b1   = (const float*)d_in[7];
    const float* a0_b2   = (const float*)d_in[9];
    const float* a0_Wg   = (const float*)d_in[10];
    const float* a0_bg   = (const float*)d_in[11];

    const int*   a1_send = (const int*)d_in[12];
    const int*   a1_recv = (const int*)d_in[13];
    const float* inv_a1  = (const float*)d_in[14];
    const float* a1_b1   = (const float*)d_in[16];
    const float* a1_b2   = (const float*)d_in[18];
    const float* a1_Wg   = (const float*)d_in[19];
    const float* a1_bg   = (const float*)d_in[20];

    const int*   i1_send = (const int*)d_in[21];
    const int*   i1_recv = (const int*)d_in[22];
    const float* inv_i1  = (const float*)d_in[23];
    const float* i1_b1   = (const float*)d_in[25];
    const float* i1_b2   = (const float*)d_in[27];
    const float* i1_Wg   = (const float*)d_in[28];
    const float* i1_bg   = (const float*)d_in[29];

    const int*   i2_send = (const int*)d_in[30];
    const int*   i2_recv = (const int*)d_in[31];
    const float* inv_i2  = (const float*)d_in[32];
    const float* i2_b1   = (const float*)d_in[34];
    const float* i2_b2   = (const float*)d_in[36];
    const float* i2_Wg   = (const float*)d_in[37];
    const float* i2_bg   = (const float*)d_in[38];

    const float* u0_b1 = (const float*)d_in[40];
    const float* u0_b2 = (const float*)d_in[42];
    const float* u1_b1 = (const float*)d_in[44];
    const float* u1_b2 = (const float*)d_in[46];
    const float* u2_b1 = (const float*)d_in[48];
    const float* u2_b2 = (const float*)d_in[50];

    const int E_a0 = in_sizes[3];
    const int E_a1 = in_sizes[12];
    const int E_i1 = in_sizes[21];
    const int E_i2 = in_sizes[30];

    // ws layout (ushort units for weights)
    unsigned short* wb = (unsigned short*)d_ws;
    const int o_w1[4] = {0, 36864, 73728, 110592};              // 9*8*512 each
    const int o_w2[4] = {147456, 163840, 180224, 196608};       // 4*8*512 each
    const int o_uw1[3] = {212992, 245760, 294912};              // 8/12/8 *8*512
    const int o_uw2[3] = {327680, 344064, 360448};              // 4*8*512 each
    float* accA = (float*)((char*)d_ws + 753664);
    float* accB = accA + (size_t)NCELLS * CDIM;

    PrepArgs pa;
    int idx = 0, cum = 0;
    auto add = [&](const void* s, int fin, int ktc, int off) {
        pa.src[idx] = (const float*)s; pa.fin[idx] = fin; pa.ktc[idx] = ktc;
        pa.dstoff[idx] = off; cum += ktc * 8; pa.tend[idx] = cum; idx++;
    };
    add(d_in[6],  259, 9,  o_w1[0]);   // a0_W1
    add(d_in[15], 262, 9,  o_w1[1]);   // a1_W1
    add(d_in[24], 259, 9,  o_w1[2]);   // i1_W1
    add(d_in[33], 262, 9,  o_w1[3]);   // i2_W1
    add(d_in[8],  128, 4,  o_w2[0]);   // a0_W2
    add(d_in[17], 128, 4,  o_w2[1]);   // a1_W2
    add(d_in[26], 128, 4,  o_w2[2]);   // i1_W2
    add(d_in[35], 128, 4,  o_w2[3]);   // i2_W2
    add(d_in[39], 256, 8,  o_uw1[0]);  // u0_W1
    add(d_in[43], 384, 12, o_uw1[1]);  // u1_W1
    add(d_in[47], 256, 8,  o_uw1[2]);  // u2_W1
    add(d_in[41], 128, 4,  o_uw2[0]);  // u0_W2
    add(d_in[45], 128, 4,  o_uw2[1]);  // u1_W2
    add(d_in[49], 128, 4,  o_uw2[2]);  // u2_W2

    prep_kernel<<<cum, 64, 0, stream>>>(pa, wb);

    const size_t accBytes = (size_t)NCELLS * CDIM * sizeof(float);
    hipMemsetAsync(accA, 0, accBytes, stream);
    hipMemsetAsync(accB, 0, accBytes, stream);

    float* out = (float*)d_out;
    const int UPD_BLK = (NCELLS + 63) / 64;

    // rank 0: a0 -> accA ; update0
    econv_kernel<3><<<(E_a0 + 63) / 64, 256, 0, stream>>>(
        f0, f0, a0_send, a0_recv, inv_a0,
        wb + o_w1[0], a0_b1, wb + o_w2[0], a0_b2, a0_Wg, a0_bg, accA, E_a0);
    update_kernel<2><<<UPD_BLK, 256, 0, stream>>>(
        f0, accA, nullptr, wb + o_uw1[0], u0_b1, wb + o_uw2[0], u0_b2, out);

    // rank 1: a1 -> accA (re-zeroed), i1 -> accB ; update1
    hipMemsetAsync(accA, 0, accBytes, stream);
    econv_kernel<6><<<(E_a1 + 63) / 64, 256, 0, stream>>>(
        f1, f1, a1_send, a1_recv, inv_a1,
        wb + o_w1[1], a1_b1, wb + o_w2[1], a1_b2, a1_Wg, a1_bg, accA, E_a1);
    econv_kernel<3><<<(E_i1 + 63) / 64, 256, 0, stream>>>(
        f0, f1, i1_send, i1_recv, inv_i1,
        wb + o_w1[2], i1_b1, wb + o_w2[2], i1_b2, i1_Wg, i1_bg, accB, E_i1);
    update_kernel<3><<<UPD_BLK, 256, 0, stream>>>(
        f1, accA, accB, wb + o_uw1[1], u1_b1, wb + o_uw2[1], u1_b2,
        out + (size_t)NCELLS * CDIM);

    // rank 2: i2 -> accA (re-zeroed) ; update2
    hipMemsetAsync(accA, 0, accBytes, stream);
    econv_kernel<6><<<(E_i2 + 63) / 64, 256, 0, stream>>>(
        f1, f2, i2_send, i2_recv, inv_i2,
        wb + o_w1[3], i2_b1, wb + o_w2[3], i2_b2, i2_Wg, i2_bg, accA, E_i2);
    update_kernel<2><<<UPD_BLK, 256, 0, stream>>>(
        f2, accA, nullptr, wb + o_uw1[2], u2_b1, wb + o_uw2[2], u2_b2,
        out + 2 * (size_t)NCELLS * CDIM);
}

// Round 2
// 1182.630 us; speedup vs baseline: 1.0891x; 1.0891x over previous
//
#include <hip/hip_runtime.h>
#include <hip/hip_bf16.h>
#include <cstdint>
#include <cstddef>

#define CDIM 128
#define NCELLS 100000

typedef __attribute__((ext_vector_type(8))) short short8;
typedef __attribute__((ext_vector_type(4))) float f32x4;

__device__ __forceinline__ unsigned short f2bf(float f) {
    unsigned u = __float_as_uint(f);
    unsigned r = u + 0x7FFFu + ((u >> 16) & 1u);
    return (unsigned short)(r >> 16);
}
__device__ __forceinline__ float bf2f(unsigned short u) {
    return __uint_as_float(((unsigned)u) << 16);
}
__device__ __forceinline__ float sigf(float x) { return 1.f / (1.f + __expf(-x)); }
__device__ __forceinline__ float siluf(float x) { return x * sigf(x); }

// ---------------------------------------------------------------------------
// Weight prep: fp32 (fin x 128) -> bf16 MFMA B-fragment order.
// frag f = ct*ktc + kt holds, for lane l, W[kt*32+(l>>4)*8+i][ct*16+(l&15)].
// ---------------------------------------------------------------------------
struct PrepArgs {
    const float* src[14];
    int dstoff[14];
    int fin[14];
    int ktc[14];
    int tend[14];
};

__global__ void prep_kernel(PrepArgs pa, unsigned short* __restrict__ wb) {
    int tile = blockIdx.x;
    int m = 0;
    while (tile >= pa.tend[m]) m++;
    int local = tile - (m == 0 ? 0 : pa.tend[m - 1]);
    int ktc = pa.ktc[m];
    int ct = local / ktc;
    int kt = local % ktc;
    int l = threadIdx.x;   // 64
    unsigned short* dst = wb + pa.dstoff[m] + (size_t)local * 512 + l * 8;
    const float* src = pa.src[m];
    int fin = pa.fin[m];
    int col = ct * 16 + (l & 15);
#pragma unroll
    for (int i = 0; i < 8; i++) {
        int k = kt * 32 + (l >> 4) * 8 + i;
        float v = (k < fin) ? src[(size_t)k * CDIM + col] : 0.f;
        dst[i] = f2bf(v);
    }
}

// ---------------------------------------------------------------------------
// CSR build: histogram -> scan -> rank
// ---------------------------------------------------------------------------
__global__ void hist_kernel(const int* __restrict__ recv, int E, int* __restrict__ bins) {
    int i = blockIdx.x * blockDim.x + threadIdx.x;
    if (i < E) atomicAdd(&bins[recv[i]], 1);
}

__global__ __launch_bounds__(1024)
void scan_kernel(const int* __restrict__ bins, int* __restrict__ offs, int NB) {
    __shared__ int wsum[16];
    __shared__ int run_s;
    const int r = blockIdx.x, t = threadIdx.x;
    const int lane = t & 63, w = t >> 6;
    const int* b = bins + (size_t)r * NB;
    int* o = offs + (size_t)r * (NB + 1);
    if (t == 0) run_s = 0;
    __syncthreads();
    for (int base = 0; base < NB; base += 1024) {
        int v = (base + t < NB) ? b[base + t] : 0;
        int x = v;
#pragma unroll
        for (int d = 1; d < 64; d <<= 1) {
            int y = __shfl_up(x, (unsigned)d, 64);
            if (lane >= d) x += y;
        }
        if (lane == 63) wsum[w] = x;
        __syncthreads();
        if (w == 0) {
            int s = (lane < 16) ? wsum[lane] : 0;
#pragma unroll
            for (int d = 1; d < 16; d <<= 1) {
                int y = __shfl_up(s, (unsigned)d, 64);
                if (lane >= d) s += y;
            }
            if (lane < 16) wsum[lane] = s;
        }
        __syncthreads();
        int woff = (w == 0) ? 0 : wsum[w - 1];
        int run = run_s;
        if (base + t < NB) o[base + t] = run + woff + x - v;
        int tot = wsum[15];
        __syncthreads();
        if (t == 0) run_s = run + tot;
        __syncthreads();
    }
    if (t == 0) o[NB] = run_s;
}

__global__ void rank_kernel(const int* __restrict__ recv, int E,
                            const int* __restrict__ offs, int* __restrict__ cur,
                            int* __restrict__ pos) {
    int i = blockIdx.x * blockDim.x + threadIdx.x;
    if (i < E) {
        int r = recv[i];
        pos[i] = offs[r] + atomicAdd(&cur[r], 1);
    }
}

// ---------------------------------------------------------------------------
// EConv: 64 edges/block. Gather -> 2-layer MFMA MLP -> gate -> write gated
// bf16 message row to recv-sorted slot msg[pos[e]]. No atomics.
// ---------------------------------------------------------------------------
template <int NINV>
__global__ __launch_bounds__(256, 4)
void econv_kernel(const float* __restrict__ xs, const float* __restrict__ xt,
                  const int* __restrict__ send, const int* __restrict__ recv,
                  const float* __restrict__ inv,
                  const unsigned short* __restrict__ W1T, const float* __restrict__ b1,
                  const unsigned short* __restrict__ W2T, const float* __restrict__ b2,
                  const float* __restrict__ Wg, const float* __restrict__ bg,
                  const int* __restrict__ pos, unsigned short* __restrict__ msg, int E)
{
    constexpr int KT1 = 9;    // K padded to 288
    constexpr int AS  = 296;  // A-tile stride (bf16)
    constexpr int YS  = 136;  // Y-tile stride
    constexpr int OS  = 136;  // out-tile stride
    __shared__ unsigned short U[64 * AS];   // union: A | (Y, O)
    __shared__ float gpart[64];
    __shared__ int   posl[64];
    unsigned short* Alds = U;
    unsigned short* Ylds = U;
    unsigned short* Olds = U + 64 * YS;

    const int t  = threadIdx.x;
    const int e0 = blockIdx.x * 64;

    // ---- gather: 4 threads/edge ----
    {
        const int el = t >> 2, q = t & 3;
        const int e  = e0 + el;
        const bool ev = (e < E);
        int si = 0, ri = 0, pp = 0;
        if (ev) { si = send[e]; ri = recv[e]; pp = pos[e]; }
        if (q == 0) { posl[el] = pp; gpart[el] = 0.f; }
        unsigned short* arow = Alds + el * AS;
        const float* sp = xs + (size_t)si * CDIM + q * 32;
        const float* tp = xt + (size_t)ri * CDIM + q * 32;
#pragma unroll
        for (int i = 0; i < 8; i++) {
            float4 v = ev ? *(const float4*)(sp + i * 4) : make_float4(0.f, 0.f, 0.f, 0.f);
            uint2 o;
            o.x = (unsigned)f2bf(v.x) | ((unsigned)f2bf(v.y) << 16);
            o.y = (unsigned)f2bf(v.z) | ((unsigned)f2bf(v.w) << 16);
            *(uint2*)(arow + q * 32 + i * 4) = o;
        }
#pragma unroll
        for (int i = 0; i < 8; i++) {
            float4 v = ev ? *(const float4*)(tp + i * 4) : make_float4(0.f, 0.f, 0.f, 0.f);
            uint2 o;
            o.x = (unsigned)f2bf(v.x) | ((unsigned)f2bf(v.y) << 16);
            o.y = (unsigned)f2bf(v.z) | ((unsigned)f2bf(v.w) << 16);
            *(uint2*)(arow + 128 + q * 32 + i * 4) = o;
        }
        if (q == 0) {
#pragma unroll
            for (int j = 0; j < NINV; j++)
                arow[256 + j] = f2bf(ev ? inv[(size_t)e * NINV + j] : 0.f);
            for (int j = NINV; j < 32; j++) arow[256 + j] = 0;
        }
    }
    __syncthreads();

    const int wave = t >> 6, lane = t & 63;
    const int wr = (wave & 1) * 32;
    const int wc = (wave >> 1) * 64;
    const int lr = lane & 15, lg = lane >> 4;

    // ---- layer 1 ----
    f32x4 a1[2][4];
#pragma unroll
    for (int mt = 0; mt < 2; mt++)
#pragma unroll
        for (int ct = 0; ct < 4; ct++) a1[mt][ct] = (f32x4){0.f, 0.f, 0.f, 0.f};

    for (int kt = 0; kt < KT1; ++kt) {
        short8 av[2];
#pragma unroll
        for (int mt = 0; mt < 2; mt++)
            av[mt] = *(const short8*)(Alds + (wr + mt * 16 + lr) * AS + kt * 32 + lg * 8);
#pragma unroll
        for (int ct = 0; ct < 4; ct++) {
            const int cg = (wc >> 4) + ct;
            short8 bv = *(const short8*)(W1T + ((size_t)(cg * KT1 + kt) * 64 + lane) * 8);
            a1[0][ct] = __builtin_amdgcn_mfma_f32_16x16x32_bf16(av[0], bv, a1[0][ct], 0, 0, 0);
            a1[1][ct] = __builtin_amdgcn_mfma_f32_16x16x32_bf16(av[1], bv, a1[1][ct], 0, 0, 0);
        }
    }
    __syncthreads();   // A fully consumed; Y overwrites A region

    // silu(y1+b1) -> Ylds
#pragma unroll
    for (int ct = 0; ct < 4; ct++) {
        const int col = wc + ct * 16 + lr;
        const float bb = b1[col];
#pragma unroll
        for (int mt = 0; mt < 2; mt++)
#pragma unroll
            for (int j = 0; j < 4; j++) {
                const int row = wr + mt * 16 + lg * 4 + j;
                Ylds[row * YS + col] = f2bf(siluf(a1[mt][ct][j] + bb));
            }
    }
    __syncthreads();

    // ---- layer 2 ----
    f32x4 a2[2][4];
#pragma unroll
    for (int mt = 0; mt < 2; mt++)
#pragma unroll
        for (int ct = 0; ct < 4; ct++) a2[mt][ct] = (f32x4){0.f, 0.f, 0.f, 0.f};

    for (int kt = 0; kt < 4; ++kt) {
        short8 av[2];
#pragma unroll
        for (int mt = 0; mt < 2; mt++)
            av[mt] = *(const short8*)(Ylds + (wr + mt * 16 + lr) * YS + kt * 32 + lg * 8);
#pragma unroll
        for (int ct = 0; ct < 4; ct++) {
            const int cg = (wc >> 4) + ct;
            short8 bv = *(const short8*)(W2T + ((size_t)(cg * 4 + kt) * 64 + lane) * 8);
            a2[0][ct] = __builtin_amdgcn_mfma_f32_16x16x32_bf16(av[0], bv, a2[0][ct], 0, 0, 0);
            a2[1][ct] = __builtin_amdgcn_mfma_f32_16x16x32_bf16(av[1], bv, a2[1][ct], 0, 0, 0);
        }
    }

    float wg[4], b2c[4];
#pragma unroll
    for (int ct = 0; ct < 4; ct++) {
        const int col = wc + ct * 16 + lr;
        wg[ct]  = Wg[col];
        b2c[ct] = b2[col];
    }
#pragma unroll
    for (int mt = 0; mt < 2; mt++)
#pragma unroll
        for (int ct = 0; ct < 4; ct++)
#pragma unroll
            for (int j = 0; j < 4; j++)
                a2[mt][ct][j] = siluf(a2[mt][ct][j] + b2c[ct]);

#pragma unroll
    for (int mt = 0; mt < 2; mt++)
#pragma unroll
        for (int j = 0; j < 4; j++) {
            float p = a2[mt][0][j] * wg[0] + a2[mt][1][j] * wg[1] +
                      a2[mt][2][j] * wg[2] + a2[mt][3][j] * wg[3];
            p += __shfl_xor(p, 1, 16);
            p += __shfl_xor(p, 2, 16);
            p += __shfl_xor(p, 4, 16);
            p += __shfl_xor(p, 8, 16);
            if (lr == 0) atomicAdd(&gpart[wr + mt * 16 + lg * 4 + j], p);
        }
    __syncthreads();

    // ---- apply gate, stage bf16 out-tile (disjoint from Y region) ----
    const float bgs = bg[0];
#pragma unroll
    for (int mt = 0; mt < 2; mt++)
#pragma unroll
        for (int j = 0; j < 4; j++) {
            const int row = wr + mt * 16 + lg * 4 + j;
            const float g = sigf(gpart[row] + bgs);
#pragma unroll
            for (int ct = 0; ct < 4; ct++)
                Olds[row * OS + wc + ct * 16 + lr] = f2bf(a2[mt][ct][j] * g);
        }
    __syncthreads();

    // ---- cooperative write to sorted slot ----
    {
        const int row = t >> 2, q = t & 3;
        if (e0 + row < E) {
            unsigned short* dst = msg + (size_t)posl[row] * CDIM + q * 32;
            const unsigned short* srcp = Olds + row * OS + q * 32;
#pragma unroll
            for (int i = 0; i < 4; i++)
                *(uint4*)(dst + i * 8) = *(const uint4*)(srcp + i * 8);
        }
    }
}

// ---------------------------------------------------------------------------
// Update MLP with fused segment-sum:
// out = f + silu([f | silu(sum m1) | silu(sum m2)] @ W1 + b1) @ W2 + b2
// msg buffers are recv-sorted; cell n owns rows [offs[n], offs[n+1]).
// ---------------------------------------------------------------------------
template <int F>
__global__ __launch_bounds__(256, F == 3 ? 3 : 4)
void update_kernel(const float* __restrict__ f,
                   const unsigned short* __restrict__ m1, const int* __restrict__ o1,
                   const unsigned short* __restrict__ m2, const int* __restrict__ o2,
                   const unsigned short* __restrict__ W1T, const float* __restrict__ b1,
                   const unsigned short* __restrict__ W2T, const float* __restrict__ b2,
                   float* __restrict__ out)
{
    constexpr int K   = F * CDIM;
    constexpr int KT1 = K / 32;
    constexpr int AS  = K + 8;
    constexpr int YS  = 136;
    __shared__ unsigned short U[64 * AS];   // union: A | Y
    unsigned short* Alds = U;
    unsigned short* Ylds = U;

    const int t  = threadIdx.x;
    const int n0 = blockIdx.x * 64;
    {
        const int rl = t >> 2, q = t & 3;
        const int n  = n0 + rl;
        const bool nv = (n < NCELLS);
        unsigned short* arow = Alds + rl * AS;
        // f part
        {
            const float* sp = f + (size_t)n * CDIM + q * 32;
#pragma unroll
            for (int i = 0; i < 8; i++) {
                float4 v = nv ? *(const float4*)(sp + i * 4) : make_float4(0.f, 0.f, 0.f, 0.f);
                uint2 o;
                o.x = (unsigned)f2bf(v.x) | ((unsigned)f2bf(v.y) << 16);
                o.y = (unsigned)f2bf(v.z) | ((unsigned)f2bf(v.w) << 16);
                *(uint2*)(arow + q * 32 + i * 4) = o;
            }
        }
        // message segment sums
#pragma unroll
        for (int p = 1; p < F; p++) {
            const unsigned short* msg = (p == 1) ? m1 : m2;
            const int* offs = (p == 1) ? o1 : o2;
            int s = 0, e = 0;
            if (nv) { s = offs[n]; e = offs[n + 1]; }
            float accv[32];
#pragma unroll
            for (int i = 0; i < 32; i++) accv[i] = 0.f;
            for (int k = s; k < e; k++) {
                const short8* mp = (const short8*)(msg + (size_t)k * CDIM + q * 32);
#pragma unroll
                for (int i = 0; i < 4; i++) {
                    short8 mv = mp[i];
#pragma unroll
                    for (int j2 = 0; j2 < 8; j2++)
                        accv[i * 8 + j2] += bf2f((unsigned short)mv[j2]);
                }
            }
            unsigned* dst32 = (unsigned*)(arow + p * CDIM + q * 32);
#pragma unroll
            for (int wds = 0; wds < 16; wds++) {
                dst32[wds] = (unsigned)f2bf(siluf(accv[2 * wds])) |
                             ((unsigned)f2bf(siluf(accv[2 * wds + 1])) << 16);
            }
        }
    }
    __syncthreads();

    const int wave = t >> 6, lane = t & 63;
    const int wr = (wave & 1) * 32;
    const int wc = (wave >> 1) * 64;
    const int lr = lane & 15, lg = lane >> 4;

    f32x4 a1[2][4];
#pragma unroll
    for (int mt = 0; mt < 2; mt++)
#pragma unroll
        for (int ct = 0; ct < 4; ct++) a1[mt][ct] = (f32x4){0.f, 0.f, 0.f, 0.f};

    for (int kt = 0; kt < KT1; ++kt) {
        short8 av[2];
#pragma unroll
        for (int mt = 0; mt < 2; mt++)
            av[mt] = *(const short8*)(Alds + (wr + mt * 16 + lr) * AS + kt * 32 + lg * 8);
#pragma unroll
        for (int ct = 0; ct < 4; ct++) {
            const int cg = (wc >> 4) + ct;
            short8 bv = *(const short8*)(W1T + ((size_t)(cg * KT1 + kt) * 64 + lane) * 8);
            a1[0][ct] = __builtin_amdgcn_mfma_f32_16x16x32_bf16(av[0], bv, a1[0][ct], 0, 0, 0);
            a1[1][ct] = __builtin_amdgcn_mfma_f32_16x16x32_bf16(av[1], bv, a1[1][ct], 0, 0, 0);
        }
    }
    __syncthreads();   // A consumed; Y overwrites

#pragma unroll
    for (int ct = 0; ct < 4; ct++) {
        const int col = wc + ct * 16 + lr;
        const float bb = b1[col];
#pragma unroll
        for (int mt = 0; mt < 2; mt++)
#pragma unroll
            for (int j = 0; j < 4; j++) {
                const int row = wr + mt * 16 + lg * 4 + j;
                Ylds[row * YS + col] = f2bf(siluf(a1[mt][ct][j] + bb));
            }
    }
    __syncthreads();

    f32x4 a2[2][4];
#pragma unroll
    for (int mt = 0; mt < 2; mt++)
#pragma unroll
        for (int ct = 0; ct < 4; ct++) a2[mt][ct] = (f32x4){0.f, 0.f, 0.f, 0.f};

    for (int kt = 0; kt < 4; ++kt) {
        short8 av[2];
#pragma unroll
        for (int mt = 0; mt < 2; mt++)
            av[mt] = *(const short8*)(Ylds + (wr + mt * 16 + lr) * YS + kt * 32 + lg * 8);
#pragma unroll
        for (int ct = 0; ct < 4; ct++) {
            const int cg = (wc >> 4) + ct;
            short8 bv = *(const short8*)(W2T + ((size_t)(cg * 4 + kt) * 64 + lane) * 8);
            a2[0][ct] = __builtin_amdgcn_mfma_f32_16x16x32_bf16(av[0], bv, a2[0][ct], 0, 0, 0);
            a2[1][ct] = __builtin_amdgcn_mfma_f32_16x16x32_bf16(av[1], bv, a2[1][ct], 0, 0, 0);
        }
    }

    float b2c[4];
#pragma unroll
    for (int ct = 0; ct < 4; ct++) b2c[ct] = b2[wc + ct * 16 + lr];

#pragma unroll
    for (int mt = 0; mt < 2; mt++)
#pragma unroll
        for (int j = 0; j < 4; j++) {
            const int row = wr + mt * 16 + lg * 4 + j;
            const int n2  = n0 + row;
            if (n2 < NCELLS) {
#pragma unroll
                for (int ct = 0; ct < 4; ct++) {
                    const int col = wc + ct * 16 + lr;
                    out[(size_t)n2 * CDIM + col] =
                        f[(size_t)n2 * CDIM + col] + a2[mt][ct][j] + b2c[ct];
                }
            }
        }
}

// ---------------------------------------------------------------------------
extern "C" void kernel_launch(void* const* d_in, const int* in_sizes, int n_in,
                              void* d_out, int out_size, void* d_ws, size_t ws_size,
                              hipStream_t stream)
{
    const float* f0 = (const float*)d_in[0];
    const float* f1 = (const float*)d_in[1];
    const float* f2 = (const float*)d_in[2];

    const int*   a0_send = (const int*)d_in[3];
    const int*   a0_recv = (const int*)d_in[4];
    const float* inv_a0  = (const float*)d_in[5];
    const float* a0_b1   = (const float*)d_in[7];
    const float* a0_b2   = (const float*)d_in[9];
    const float* a0_Wg   = (const float*)d_in[10];
    const float* a0_bg   = (const float*)d_in[11];

    const int*   a1_send = (const int*)d_in[12];
    const int*   a1_recv = (const int*)d_in[13];
    const float* inv_a1  = (const float*)d_in[14];
    const float* a1_b1   = (const float*)d_in[16];
    const float* a1_b2   = (const float*)d_in[18];
    const float* a1_Wg   = (const float*)d_in[19];
    const float* a1_bg   = (const float*)d_in[20];

    const int*   i1_send = (const int*)d_in[21];
    const int*   i1_recv = (const int*)d_in[22];
    const float* inv_i1  = (const float*)d_in[23];
    const float* i1_b1   = (const float*)d_in[25];
    const float* i1_b2   = (const float*)d_in[27];
    const float* i1_Wg   = (const float*)d_in[28];
    const float* i1_bg   = (const float*)d_in[29];

    const int*   i2_send = (const int*)d_in[30];
    const int*   i2_recv = (const int*)d_in[31];
    const float* inv_i2  = (const float*)d_in[32];
    const float* i2_b1   = (const float*)d_in[34];
    const float* i2_b2   = (const float*)d_in[36];
    const float* i2_Wg   = (const float*)d_in[37];
    const float* i2_bg   = (const float*)d_in[38];

    const float* u0_b1 = (const float*)d_in[40];
    const float* u0_b2 = (const float*)d_in[42];
    const float* u1_b1 = (const float*)d_in[44];
    const float* u1_b2 = (const float*)d_in[46];
    const float* u2_b1 = (const float*)d_in[48];
    const float* u2_b2 = (const float*)d_in[50];

    const int E_a0 = in_sizes[3];
    const int E_a1 = in_sizes[12];
    const int E_i1 = in_sizes[21];
    const int E_i2 = in_sizes[30];
    const int Es[4] = {E_a0, E_a1, E_i1, E_i2};
    const int* recvs[4] = {a0_recv, a1_recv, i1_recv, i2_recv};

    // ---- ws bump allocator ----
    char* base = (char*)d_ws;
    size_t off = 0;
    auto alloc = [&](size_t bytes) -> char* {
        off = (off + 255) & ~(size_t)255;
        char* p = base + off;
        off += bytes;
        return p;
    };
    unsigned short* wb  = (unsigned short*)alloc(753664);
    int* offs_all = (int*)alloc((size_t)4 * (NCELLS + 1) * sizeof(int));
    int* bins_all = (int*)alloc((size_t)4 * NCELLS * sizeof(int));   // also cursor
    int* pos_all[4];
    for (int r = 0; r < 4; r++) pos_all[r] = (int*)alloc((size_t)Es[r] * sizeof(int));
    unsigned short* msgA = (unsigned short*)alloc((size_t)400000 * CDIM * sizeof(unsigned short));
    unsigned short* msgB = (unsigned short*)alloc((size_t)200000 * CDIM * sizeof(unsigned short));

    // ---- weight prep ----
    const int o_w1[4]  = {0, 36864, 73728, 110592};
    const int o_w2[4]  = {147456, 163840, 180224, 196608};
    const int o_uw1[3] = {212992, 245760, 294912};
    const int o_uw2[3] = {327680, 344064, 360448};

    PrepArgs pa;
    int idx = 0, cum = 0;
    auto add = [&](const void* s, int fin, int ktc, int woff) {
        pa.src[idx] = (const float*)s; pa.fin[idx] = fin; pa.ktc[idx] = ktc;
        pa.dstoff[idx] = woff; cum += ktc * 8; pa.tend[idx] = cum; idx++;
    };
    add(d_in[6],  259, 9,  o_w1[0]);
    add(d_in[15], 262, 9,  o_w1[1]);
    add(d_in[24], 259, 9,  o_w1[2]);
    add(d_in[33], 262, 9,  o_w1[3]);
    add(d_in[8],  128, 4,  o_w2[0]);
    add(d_in[17], 128, 4,  o_w2[1]);
    add(d_in[26], 128, 4,  o_w2[2]);
    add(d_in[35], 128, 4,  o_w2[3]);
    add(d_in[39], 256, 8,  o_uw1[0]);
    add(d_in[43], 384, 12, o_uw1[1]);
    add(d_in[47], 256, 8,  o_uw1[2]);
    add(d_in[41], 128, 4,  o_uw2[0]);
    add(d_in[45], 128, 4,  o_uw2[1]);
    add(d_in[49], 128, 4,  o_uw2[2]);
    prep_kernel<<<cum, 64, 0, stream>>>(pa, wb);

    // ---- CSR build for all 4 relations ----
    hipMemsetAsync(bins_all, 0, (size_t)4 * NCELLS * sizeof(int), stream);
    for (int r = 0; r < 4; r++)
        hist_kernel<<<(Es[r] + 255) / 256, 256, 0, stream>>>(recvs[r], Es[r], bins_all + (size_t)r * NCELLS);
    scan_kernel<<<4, 1024, 0, stream>>>(bins_all, offs_all, NCELLS);
    hipMemsetAsync(bins_all, 0, (size_t)4 * NCELLS * sizeof(int), stream);
    for (int r = 0; r < 4; r++)
        rank_kernel<<<(Es[r] + 255) / 256, 256, 0, stream>>>(
            recvs[r], Es[r], offs_all + (size_t)r * (NCELLS + 1),
            bins_all + (size_t)r * NCELLS, pos_all[r]);

    const int* offs0 = offs_all;
    const int* offs1 = offs_all + (size_t)1 * (NCELLS + 1);
    const int* offs2 = offs_all + (size_t)2 * (NCELLS + 1);
    const int* offs3 = offs_all + (size_t)3 * (NCELLS + 1);

    float* out = (float*)d_out;
    const int UPD_BLK = (NCELLS + 63) / 64;

    // rank 0
    econv_kernel<3><<<(E_a0 + 63) / 64, 256, 0, stream>>>(
        f0, f0, a0_send, a0_recv, inv_a0,
        wb + o_w1[0], a0_b1, wb + o_w2[0], a0_b2, a0_Wg, a0_bg, pos_all[0], msgA, E_a0);
    update_kernel<2><<<UPD_BLK, 256, 0, stream>>>(
        f0, msgA, offs0, nullptr, nullptr,
        wb + o_uw1[0], u0_b1, wb + o_uw2[0], u0_b2, out);

    // rank 1
    econv_kernel<6><<<(E_a1 + 63) / 64, 256, 0, stream>>>(
        f1, f1, a1_send, a1_recv, inv_a1,
        wb + o_w1[1], a1_b1, wb + o_w2[1], a1_b2, a1_Wg, a1_bg, pos_all[1], msgA, E_a1);
    econv_kernel<3><<<(E_i1 + 63) / 64, 256, 0, stream>>>(
        f0, f1, i1_send, i1_recv, inv_i1,
        wb + o_w1[2], i1_b1, wb + o_w2[2], i1_b2, i1_Wg, i1_bg, pos_all[2], msgB, E_i1);
    update_kernel<3><<<UPD_BLK, 256, 0, stream>>>(
        f1, msgA, offs1, msgB, offs2,
        wb + o_uw1[1], u1_b1, wb + o_uw2[1], u1_b2, out + (size_t)NCELLS * CDIM);

    // rank 2
    econv_kernel<6><<<(E_i2 + 63) / 64, 256, 0, stream>>>(
        f1, f2, i2_send, i2_recv, inv_i2,
        wb + o_w1[3], i2_b1, wb + o_w2[3], i2_b2, i2_Wg, i2_bg, pos_all[3], msgA, E_i2);
    update_kernel<2><<<UPD_BLK, 256, 0, stream>>>(
        f2, msgA, offs3, nullptr, nullptr,
        wb + o_uw1[2], u2_b1, wb + o_uw2[2], u2_b2, out + 2 * (size_t)NCELLS * CDIM);
}

// Round 3
// 924.046 us; speedup vs baseline: 1.3939x; 1.2798x over previous
//
#include <hip/hip_runtime.h>
#include <hip/hip_bf16.h>
#include <cstdint>
#include <cstddef>

#define CDIM 128
#define NCELLS 100000

typedef __attribute__((ext_vector_type(8))) short short8;
typedef __attribute__((ext_vector_type(4))) float f32x4;

__device__ __forceinline__ unsigned short f2bf(float f) {
    unsigned u = __float_as_uint(f);
    unsigned r = u + 0x7FFFu + ((u >> 16) & 1u);
    return (unsigned short)(r >> 16);
}
__device__ __forceinline__ float bf2f(unsigned short u) {
    return __uint_as_float(((unsigned)u) << 16);
}
__device__ __forceinline__ float sigf(float x) { return 1.f / (1.f + __expf(-x)); }
__device__ __forceinline__ float siluf(float x) { return x * sigf(x); }

// async global->LDS, 16B per lane. LDS dest = wave-uniform base + lane*16.
__device__ __forceinline__ void load_lds16(const void* g, void* ldsbase, int lane) {
#if defined(__has_builtin) && __has_builtin(__builtin_amdgcn_global_load_lds)
    __builtin_amdgcn_global_load_lds(
        (const __attribute__((address_space(1))) unsigned int*)(uintptr_t)g,
        (__attribute__((address_space(3))) unsigned int*)(uintptr_t)ldsbase,
        16, 0, 0);
#else
    *(uint4*)((char*)ldsbase + lane * 16) = *(const uint4*)g;
#endif
}

// ---------------------------------------------------------------------------
// fp32 -> bf16 table conversion (8 elems/thread)
// ---------------------------------------------------------------------------
__global__ void f2bf_kernel(const float* __restrict__ src, unsigned short* __restrict__ dst, int n8) {
    int i = blockIdx.x * blockDim.x + threadIdx.x;
    if (i >= n8) return;
    const float4* s = (const float4*)src + (size_t)i * 2;
    float4 a = s[0], b = s[1];
    uint4 o;
    o.x = (unsigned)f2bf(a.x) | ((unsigned)f2bf(a.y) << 16);
    o.y = (unsigned)f2bf(a.z) | ((unsigned)f2bf(a.w) << 16);
    o.z = (unsigned)f2bf(b.x) | ((unsigned)f2bf(b.y) << 16);
    o.w = (unsigned)f2bf(b.z) | ((unsigned)f2bf(b.w) << 16);
    ((uint4*)dst)[i] = o;
}

// ---------------------------------------------------------------------------
// Weight prep: fp32 (fin x 128) -> bf16 MFMA B-fragment order.
// ---------------------------------------------------------------------------
struct PrepArgs {
    const float* src[14];
    int dstoff[14];
    int fin[14];
    int ktc[14];
    int tend[14];
};

__global__ void prep_kernel(PrepArgs pa, unsigned short* __restrict__ wb) {
    int tile = blockIdx.x;
    int m = 0;
    while (tile >= pa.tend[m]) m++;
    int local = tile - (m == 0 ? 0 : pa.tend[m - 1]);
    int ktc = pa.ktc[m];
    int ct = local / ktc;
    int kt = local % ktc;
    int l = threadIdx.x;   // 64
    unsigned short* dst = wb + pa.dstoff[m] + (size_t)local * 512 + l * 8;
    const float* src = pa.src[m];
    int fin = pa.fin[m];
    int col = ct * 16 + (l & 15);
#pragma unroll
    for (int i = 0; i < 8; i++) {
        int k = kt * 32 + (l >> 4) * 8 + i;
        float v = (k < fin) ? src[(size_t)k * CDIM + col] : 0.f;
        dst[i] = f2bf(v);
    }
}

// ---------------------------------------------------------------------------
// CSR build: fused histogram -> scan -> fused rank
// ---------------------------------------------------------------------------
__global__ void hist4_kernel(const int* __restrict__ r0, const int* __restrict__ r1,
                             const int* __restrict__ r2, const int* __restrict__ r3,
                             int E0, int E1, int E2, int E3, int* __restrict__ bins) {
    int i = blockIdx.x * blockDim.x + threadIdx.x;
    const int c1 = E0, c2 = c1 + E1, c3 = c2 + E2, c4 = c3 + E3;
    if (i >= c4) return;
    const int* r; int* b; int j;
    if (i < c1)      { r = r0; j = i;      b = bins; }
    else if (i < c2) { r = r1; j = i - c1; b = bins + (size_t)NCELLS; }
    else if (i < c3) { r = r2; j = i - c2; b = bins + (size_t)2 * NCELLS; }
    else             { r = r3; j = i - c3; b = bins + (size_t)3 * NCELLS; }
    atomicAdd(&b[r[j]], 1);
}

__global__ __launch_bounds__(1024)
void scan_kernel(const int* __restrict__ bins, int* __restrict__ offs, int NB) {
    __shared__ int wsum[16];
    __shared__ int run_s;
    const int r = blockIdx.x, t = threadIdx.x;
    const int lane = t & 63, w = t >> 6;
    const int* b = bins + (size_t)r * NB;
    int* o = offs + (size_t)r * (NB + 1);
    if (t == 0) run_s = 0;
    __syncthreads();
    for (int base = 0; base < NB; base += 1024) {
        int v = (base + t < NB) ? b[base + t] : 0;
        int x = v;
#pragma unroll
        for (int d = 1; d < 64; d <<= 1) {
            int y = __shfl_up(x, (unsigned)d, 64);
            if (lane >= d) x += y;
        }
        if (lane == 63) wsum[w] = x;
        __syncthreads();
        if (w == 0) {
            int s = (lane < 16) ? wsum[lane] : 0;
#pragma unroll
            for (int d = 1; d < 16; d <<= 1) {
                int y = __shfl_up(s, (unsigned)d, 64);
                if (lane >= d) s += y;
            }
            if (lane < 16) wsum[lane] = s;
        }
        __syncthreads();
        int woff = (w == 0) ? 0 : wsum[w - 1];
        int run = run_s;
        if (base + t < NB) o[base + t] = run + woff + x - v;
        int tot = wsum[15];
        __syncthreads();
        if (t == 0) run_s = run + tot;
        __syncthreads();
    }
    if (t == 0) o[NB] = run_s;
}

__global__ void rank4_kernel(const int* __restrict__ r0, const int* __restrict__ r1,
                             const int* __restrict__ r2, const int* __restrict__ r3,
                             int E0, int E1, int E2, int E3,
                             const int* __restrict__ offs, int* __restrict__ cur,
                             int* __restrict__ p0, int* __restrict__ p1,
                             int* __restrict__ p2, int* __restrict__ p3) {
    int i = blockIdx.x * blockDim.x + threadIdx.x;
    const int c1 = E0, c2 = c1 + E1, c3 = c2 + E2, c4 = c3 + E3;
    if (i >= c4) return;
    const int* r; const int* o; int* c; int* p; int j;
    if (i < c1)      { r = r0; j = i;      o = offs;                         c = cur;                         p = p0; }
    else if (i < c2) { r = r1; j = i - c1; o = offs + (size_t)(NCELLS + 1);  c = cur + (size_t)NCELLS;        p = p1; }
    else if (i < c3) { r = r2; j = i - c2; o = offs + (size_t)2*(NCELLS+1);  c = cur + (size_t)2 * NCELLS;    p = p2; }
    else             { r = r3; j = i - c3; o = offs + (size_t)3*(NCELLS+1);  c = cur + (size_t)3 * NCELLS;    p = p3; }
    int v = r[j];
    p[j] = o[v] + atomicAdd(&c[v], 1);
}

// ---------------------------------------------------------------------------
// EConv: 64 edges/block. Async-stage [x_s|x_t] bf16 rows via global_load_lds
// with source-side XOR swizzle; inv in a small padded tile (kt=8).
// 2-layer MFMA MLP -> gate -> write gated bf16 row to msg[pos[e]].
// ---------------------------------------------------------------------------
template <int NINV>
__global__ __launch_bounds__(256, 4)
void econv_kernel(const unsigned short* __restrict__ fbs, const unsigned short* __restrict__ fbt,
                  const int* __restrict__ send, const int* __restrict__ recv,
                  const float* __restrict__ inv,
                  const unsigned short* __restrict__ W1T, const float* __restrict__ b1,
                  const unsigned short* __restrict__ W2T, const float* __restrict__ b2,
                  const float* __restrict__ Wg, const float* __restrict__ bg,
                  const int* __restrict__ pos, unsigned short* __restrict__ msg, int E)
{
    constexpr int YS = 136;                 // Y/O stride (bf16)
    __shared__ unsigned short U[64 * 256];  // union: A_main (swz) | Y | O
    __shared__ unsigned short A_inv[64 * 40];
    __shared__ float gpart[64];
    __shared__ int   posl[64];

    const int t  = threadIdx.x;
    const int l  = t & 63, w = t >> 6;
    const int e0 = blockIdx.x * 64;

    // ---- async stage A_main: wave w stages rows w*16 .. w*16+15 ----
    {
        const int s    = l & 31;           // 16B slot within 512B row
        const int half = s & 16;           // 0: send/x_s half, 1: recv/x_t half
        const unsigned short* fbh = half ? fbt : fbs;
        const int* idxp = half ? recv : send;
#pragma unroll
        for (int i = 0; i < 8; i++) {
            const int r = w * 16 + i * 2 + (l >> 5);
            int e = e0 + r; e = (e < E) ? e : (E - 1);
            const int u15 = (s & 8) | ((s ^ r) & 7);   // swizzled slot within half
            const unsigned short* g = fbh + (size_t)idxp[e] * CDIM + u15 * 8;
            load_lds16(g, U + (w * 16 + i * 2) * 256, l);
        }
    }
    // ---- inv tile + posl + gpart ----
    if (t < 64) {
        int e = e0 + t;
        e = (e < E) ? e : (E - 1);
        posl[t]  = pos[e];
        gpart[t] = 0.f;
        unsigned short* ar = A_inv + t * 40;
#pragma unroll
        for (int j = 0; j < NINV; j++) ar[j] = f2bf(inv[(size_t)e * NINV + j]);
#pragma unroll
        for (int j = NINV; j < 32; j++) ar[j] = 0;
    }
    __syncthreads();

    const int lr = l & 15, lg = l >> 4;
    const int wr = (w & 1) * 32;
    const int wc = (w >> 1) * 64;

    // ---- layer 1: A(64x288) @ W1(288x128), kt 0-7 swizzled main, kt 8 inv ----
    f32x4 a1[2][4];
#pragma unroll
    for (int mt = 0; mt < 2; mt++)
#pragma unroll
        for (int ct = 0; ct < 4; ct++) a1[mt][ct] = (f32x4){0.f, 0.f, 0.f, 0.f};

#pragma unroll
    for (int kt = 0; kt < 8; ++kt) {
        short8 av[2];
        const int c = kt * 4 + lg;
#pragma unroll
        for (int mt = 0; mt < 2; mt++) {
            const int row = wr + mt * 16 + lr;
            const int sr  = (c & 24) | ((c ^ row) & 7);
            av[mt] = *(const short8*)(U + row * 256 + sr * 8);
        }
#pragma unroll
        for (int ct = 0; ct < 4; ct++) {
            const int cg = (wc >> 4) + ct;
            short8 bv = *(const short8*)(W1T + ((size_t)(cg * 9 + kt) * 64 + l) * 8);
            a1[0][ct] = __builtin_amdgcn_mfma_f32_16x16x32_bf16(av[0], bv, a1[0][ct], 0, 0, 0);
            a1[1][ct] = __builtin_amdgcn_mfma_f32_16x16x32_bf16(av[1], bv, a1[1][ct], 0, 0, 0);
        }
    }
    {   // kt = 8: invariants
        short8 av[2];
#pragma unroll
        for (int mt = 0; mt < 2; mt++)
            av[mt] = *(const short8*)(A_inv + (wr + mt * 16 + lr) * 40 + lg * 8);
#pragma unroll
        for (int ct = 0; ct < 4; ct++) {
            const int cg = (wc >> 4) + ct;
            short8 bv = *(const short8*)(W1T + ((size_t)(cg * 9 + 8) * 64 + l) * 8);
            a1[0][ct] = __builtin_amdgcn_mfma_f32_16x16x32_bf16(av[0], bv, a1[0][ct], 0, 0, 0);
            a1[1][ct] = __builtin_amdgcn_mfma_f32_16x16x32_bf16(av[1], bv, a1[1][ct], 0, 0, 0);
        }
    }
    __syncthreads();   // A_main fully consumed; Y overwrites U

    // silu(y1+b1) -> Y (stride YS)
#pragma unroll
    for (int ct = 0; ct < 4; ct++) {
        const int col = wc + ct * 16 + lr;
        const float bb = b1[col];
#pragma unroll
        for (int mt = 0; mt < 2; mt++)
#pragma unroll
            for (int j = 0; j < 4; j++) {
                const int row = wr + mt * 16 + lg * 4 + j;
                U[row * YS + col] = f2bf(siluf(a1[mt][ct][j] + bb));
            }
    }
    __syncthreads();

    // ---- layer 2: Y(64x128) @ W2(128x128) ----
    f32x4 a2[2][4];
#pragma unroll
    for (int mt = 0; mt < 2; mt++)
#pragma unroll
        for (int ct = 0; ct < 4; ct++) a2[mt][ct] = (f32x4){0.f, 0.f, 0.f, 0.f};

#pragma unroll
    for (int kt = 0; kt < 4; ++kt) {
        short8 av[2];
#pragma unroll
        for (int mt = 0; mt < 2; mt++)
            av[mt] = *(const short8*)(U + (wr + mt * 16 + lr) * YS + kt * 32 + lg * 8);
#pragma unroll
        for (int ct = 0; ct < 4; ct++) {
            const int cg = (wc >> 4) + ct;
            short8 bv = *(const short8*)(W2T + ((size_t)(cg * 4 + kt) * 64 + l) * 8);
            a2[0][ct] = __builtin_amdgcn_mfma_f32_16x16x32_bf16(av[0], bv, a2[0][ct], 0, 0, 0);
            a2[1][ct] = __builtin_amdgcn_mfma_f32_16x16x32_bf16(av[1], bv, a2[1][ct], 0, 0, 0);
        }
    }

    float wg[4], b2c[4];
#pragma unroll
    for (int ct = 0; ct < 4; ct++) {
        const int col = wc + ct * 16 + lr;
        wg[ct]  = Wg[col];
        b2c[ct] = b2[col];
    }
#pragma unroll
    for (int mt = 0; mt < 2; mt++)
#pragma unroll
        for (int ct = 0; ct < 4; ct++)
#pragma unroll
            for (int j = 0; j < 4; j++)
                a2[mt][ct][j] = siluf(a2[mt][ct][j] + b2c[ct]);

#pragma unroll
    for (int mt = 0; mt < 2; mt++)
#pragma unroll
        for (int j = 0; j < 4; j++) {
            float p = a2[mt][0][j] * wg[0] + a2[mt][1][j] * wg[1] +
                      a2[mt][2][j] * wg[2] + a2[mt][3][j] * wg[3];
            p += __shfl_xor(p, 1, 16);
            p += __shfl_xor(p, 2, 16);
            p += __shfl_xor(p, 4, 16);
            p += __shfl_xor(p, 8, 16);
            if (lr == 0) atomicAdd(&gpart[wr + mt * 16 + lg * 4 + j], p);
        }
    __syncthreads();   // all Y reads + gate partials complete; O overwrites U

    const float bgs = bg[0];
#pragma unroll
    for (int mt = 0; mt < 2; mt++)
#pragma unroll
        for (int j = 0; j < 4; j++) {
            const int row = wr + mt * 16 + lg * 4 + j;
            const float g = sigf(gpart[row] + bgs);
#pragma unroll
            for (int ct = 0; ct < 4; ct++)
                U[row * YS + wc + ct * 16 + lr] = f2bf(a2[mt][ct][j] * g);
        }
    __syncthreads();

    // ---- cooperative write to sorted slot ----
    {
        const int row = t >> 2, q = t & 3;
        if (e0 + row < E) {
            unsigned short* dst = msg + (size_t)posl[row] * CDIM + q * 32;
            const unsigned short* srcp = U + row * YS + q * 32;
#pragma unroll
            for (int i = 0; i < 4; i++)
                *(uint4*)(dst + i * 8) = *(const uint4*)(srcp + i * 8);
        }
    }
}

// ---------------------------------------------------------------------------
// Update MLP with fused segment-sum:
// out = f + silu([f | silu(sum m1) | silu(sum m2)] @ W1 + b1) @ W2 + b2
// ---------------------------------------------------------------------------
template <int F>
__global__ __launch_bounds__(256, F == 3 ? 3 : 4)
void update_kernel(const float* __restrict__ f, const unsigned short* __restrict__ fb,
                   const unsigned short* __restrict__ m1, const int* __restrict__ o1,
                   const unsigned short* __restrict__ m2, const int* __restrict__ o2,
                   const unsigned short* __restrict__ W1T, const float* __restrict__ b1,
                   const unsigned short* __restrict__ W2T, const float* __restrict__ b2,
                   float* __restrict__ out)
{
    constexpr int K   = F * CDIM;
    constexpr int KT1 = K / 32;
    constexpr int AS  = K + 8;
    constexpr int YS  = 136;
    __shared__ unsigned short U[64 * AS];   // union: A | Y
    unsigned short* Alds = U;
    unsigned short* Ylds = U;

    const int t  = threadIdx.x;
    const int n0 = blockIdx.x * 64;
    {
        const int rl = t >> 2, q = t & 3;
        const int n  = n0 + rl;
        const bool nv = (n < NCELLS);
        const int nc = nv ? n : (NCELLS - 1);
        unsigned short* arow = Alds + rl * AS;
        // f part: direct bf16 copy
        {
            const uint4* sp = (const uint4*)(fb + (size_t)nc * CDIM + q * 32);
            uint4* dp = (uint4*)(arow + q * 32);
#pragma unroll
            for (int i = 0; i < 4; i++) dp[i] = sp[i];
        }
        // message segment sums
#pragma unroll
        for (int p = 1; p < F; p++) {
            const unsigned short* msg = (p == 1) ? m1 : m2;
            const int* offs = (p == 1) ? o1 : o2;
            int s = 0, e = 0;
            if (nv) { s = offs[n]; e = offs[n + 1]; }
            float accv[32];
#pragma unroll
            for (int i = 0; i < 32; i++) accv[i] = 0.f;
            for (int k = s; k < e; k++) {
                const short8* mp = (const short8*)(msg + (size_t)k * CDIM + q * 32);
#pragma unroll
                for (int i = 0; i < 4; i++) {
                    short8 mv = mp[i];
#pragma unroll
                    for (int j2 = 0; j2 < 8; j2++)
                        accv[i * 8 + j2] += bf2f((unsigned short)mv[j2]);
                }
            }
            unsigned* dst32 = (unsigned*)(arow + p * CDIM + q * 32);
#pragma unroll
            for (int wds = 0; wds < 16; wds++) {
                dst32[wds] = (unsigned)f2bf(siluf(accv[2 * wds])) |
                             ((unsigned)f2bf(siluf(accv[2 * wds + 1])) << 16);
            }
        }
    }
    __syncthreads();

    const int wave = t >> 6, lane = t & 63;
    const int wr = (wave & 1) * 32;
    const int wc = (wave >> 1) * 64;
    const int lr = lane & 15, lg = lane >> 4;

    f32x4 a1[2][4];
#pragma unroll
    for (int mt = 0; mt < 2; mt++)
#pragma unroll
        for (int ct = 0; ct < 4; ct++) a1[mt][ct] = (f32x4){0.f, 0.f, 0.f, 0.f};

    for (int kt = 0; kt < KT1; ++kt) {
        short8 av[2];
#pragma unroll
        for (int mt = 0; mt < 2; mt++)
            av[mt] = *(const short8*)(Alds + (wr + mt * 16 + lr) * AS + kt * 32 + lg * 8);
#pragma unroll
        for (int ct = 0; ct < 4; ct++) {
            const int cg = (wc >> 4) + ct;
            short8 bv = *(const short8*)(W1T + ((size_t)(cg * KT1 + kt) * 64 + lane) * 8);
            a1[0][ct] = __builtin_amdgcn_mfma_f32_16x16x32_bf16(av[0], bv, a1[0][ct], 0, 0, 0);
            a1[1][ct] = __builtin_amdgcn_mfma_f32_16x16x32_bf16(av[1], bv, a1[1][ct], 0, 0, 0);
        }
    }
    __syncthreads();   // A consumed; Y overwrites

#pragma unroll
    for (int ct = 0; ct < 4; ct++) {
        const int col = wc + ct * 16 + lr;
        const float bb = b1[col];
#pragma unroll
        for (int mt = 0; mt < 2; mt++)
#pragma unroll
            for (int j = 0; j < 4; j++) {
                const int row = wr + mt * 16 + lg * 4 + j;
                Ylds[row * YS + col] = f2bf(siluf(a1[mt][ct][j] + bb));
            }
    }
    __syncthreads();

    f32x4 a2[2][4];
#pragma unroll
    for (int mt = 0; mt < 2; mt++)
#pragma unroll
        for (int ct = 0; ct < 4; ct++) a2[mt][ct] = (f32x4){0.f, 0.f, 0.f, 0.f};

    for (int kt = 0; kt < 4; ++kt) {
        short8 av[2];
#pragma unroll
        for (int mt = 0; mt < 2; mt++)
            av[mt] = *(const short8*)(Ylds + (wr + mt * 16 + lr) * YS + kt * 32 + lg * 8);
#pragma unroll
        for (int ct = 0; ct < 4; ct++) {
            const int cg = (wc >> 4) + ct;
            short8 bv = *(const short8*)(W2T + ((size_t)(cg * 4 + kt) * 64 + lane) * 8);
            a2[0][ct] = __builtin_amdgcn_mfma_f32_16x16x32_bf16(av[0], bv, a2[0][ct], 0, 0, 0);
            a2[1][ct] = __builtin_amdgcn_mfma_f32_16x16x32_bf16(av[1], bv, a2[1][ct], 0, 0, 0);
        }
    }

    float b2c[4];
#pragma unroll
    for (int ct = 0; ct < 4; ct++) b2c[ct] = b2[wc + ct * 16 + lr];

#pragma unroll
    for (int mt = 0; mt < 2; mt++)
#pragma unroll
        for (int j = 0; j < 4; j++) {
            const int row = wr + mt * 16 + lg * 4 + j;
            const int n2  = n0 + row;
            if (n2 < NCELLS) {
#pragma unroll
                for (int ct = 0; ct < 4; ct++) {
                    const int col = wc + ct * 16 + lr;
                    out[(size_t)n2 * CDIM + col] =
                        f[(size_t)n2 * CDIM + col] + a2[mt][ct][j] + b2c[ct];
                }
            }
        }
}

// ---------------------------------------------------------------------------
extern "C" void kernel_launch(void* const* d_in, const int* in_sizes, int n_in,
                              void* d_out, int out_size, void* d_ws, size_t ws_size,
                              hipStream_t stream)
{
    const float* f0 = (const float*)d_in[0];
    const float* f1 = (const float*)d_in[1];
    const float* f2 = (const float*)d_in[2];

    const int*   a0_send = (const int*)d_in[3];
    const int*   a0_recv = (const int*)d_in[4];
    const float* inv_a0  = (const float*)d_in[5];
    const float* a0_b1   = (const float*)d_in[7];
    const float* a0_b2   = (const float*)d_in[9];
    const float* a0_Wg   = (const float*)d_in[10];
    const float* a0_bg   = (const float*)d_in[11];

    const int*   a1_send = (const int*)d_in[12];
    const int*   a1_recv = (const int*)d_in[13];
    const float* inv_a1  = (const float*)d_in[14];
    const float* a1_b1   = (const float*)d_in[16];
    const float* a1_b2   = (const float*)d_in[18];
    const float* a1_Wg   = (const float*)d_in[19];
    const float* a1_bg   = (const float*)d_in[20];

    const int*   i1_send = (const int*)d_in[21];
    const int*   i1_recv = (const int*)d_in[22];
    const float* inv_i1  = (const float*)d_in[23];
    const float* i1_b1   = (const float*)d_in[25];
    const float* i1_b2   = (const float*)d_in[27];
    const float* i1_Wg   = (const float*)d_in[28];
    const float* i1_bg   = (const float*)d_in[29];

    const int*   i2_send = (const int*)d_in[30];
    const int*   i2_recv = (const int*)d_in[31];
    const float* inv_i2  = (const float*)d_in[32];
    const float* i2_b1   = (const float*)d_in[34];
    const float* i2_b2   = (const float*)d_in[36];
    const float* i2_Wg   = (const float*)d_in[37];
    const float* i2_bg   = (const float*)d_in[38];

    const float* u0_b1 = (const float*)d_in[40];
    const float* u0_b2 = (const float*)d_in[42];
    const float* u1_b1 = (const float*)d_in[44];
    const float* u1_b2 = (const float*)d_in[46];
    const float* u2_b1 = (const float*)d_in[48];
    const float* u2_b2 = (const float*)d_in[50];

    const int E_a0 = in_sizes[3];
    const int E_a1 = in_sizes[12];
    const int E_i1 = in_sizes[21];
    const int E_i2 = in_sizes[30];

    // ---- ws bump allocator ----
    char* base = (char*)d_ws;
    size_t off = 0;
    auto alloc = [&](size_t bytes) -> char* {
        off = (off + 255) & ~(size_t)255;
        char* p = base + off;
        off += bytes;
        return p;
    };
    unsigned short* wb  = (unsigned short*)alloc(753664);
    int* offs_all = (int*)alloc((size_t)4 * (NCELLS + 1) * sizeof(int));
    int* bins_all = (int*)alloc((size_t)4 * NCELLS * sizeof(int));   // also cursor
    int* pos0 = (int*)alloc((size_t)E_a0 * sizeof(int));
    int* pos1 = (int*)alloc((size_t)E_a1 * sizeof(int));
    int* pos2 = (int*)alloc((size_t)E_i1 * sizeof(int));
    int* pos3 = (int*)alloc((size_t)E_i2 * sizeof(int));
    unsigned short* msgA = (unsigned short*)alloc((size_t)400000 * CDIM * sizeof(unsigned short));
    unsigned short* msgB = (unsigned short*)alloc((size_t)200000 * CDIM * sizeof(unsigned short));
    unsigned short* fb0  = (unsigned short*)alloc((size_t)NCELLS * CDIM * sizeof(unsigned short));
    unsigned short* fb1  = (unsigned short*)alloc((size_t)NCELLS * CDIM * sizeof(unsigned short));
    unsigned short* fb2  = msgB;   // aliased: f2 conversion runs AFTER update1 (last msgB reader)

    // ---- weight prep ----
    const int o_w1[4]  = {0, 36864, 73728, 110592};
    const int o_w2[4]  = {147456, 163840, 180224, 196608};
    const int o_uw1[3] = {212992, 245760, 294912};
    const int o_uw2[3] = {327680, 344064, 360448};

    PrepArgs pa;
    int idx = 0, cum = 0;
    auto add = [&](const void* s, int fin, int ktc, int woff) {
        pa.src[idx] = (const float*)s; pa.fin[idx] = fin; pa.ktc[idx] = ktc;
        pa.dstoff[idx] = woff; cum += ktc * 8; pa.tend[idx] = cum; idx++;
    };
    add(d_in[6],  259, 9,  o_w1[0]);
    add(d_in[15], 262, 9,  o_w1[1]);
    add(d_in[24], 259, 9,  o_w1[2]);
    add(d_in[33], 262, 9,  o_w1[3]);
    add(d_in[8],  128, 4,  o_w2[0]);
    add(d_in[17], 128, 4,  o_w2[1]);
    add(d_in[26], 128, 4,  o_w2[2]);
    add(d_in[35], 128, 4,  o_w2[3]);
    add(d_in[39], 256, 8,  o_uw1[0]);
    add(d_in[43], 384, 12, o_uw1[1]);
    add(d_in[47], 256, 8,  o_uw1[2]);
    add(d_in[41], 128, 4,  o_uw2[0]);
    add(d_in[45], 128, 4,  o_uw2[1]);
    add(d_in[49], 128, 4,  o_uw2[2]);
    prep_kernel<<<cum, 64, 0, stream>>>(pa, wb);

    // ---- bf16 feature tables (f2 deferred: fb2 aliases msgB) ----
    const int n8 = NCELLS * CDIM / 8;
    const int CONV_BLK = (n8 + 255) / 256;
    f2bf_kernel<<<CONV_BLK, 256, 0, stream>>>(f0, fb0, n8);
    f2bf_kernel<<<CONV_BLK, 256, 0, stream>>>(f1, fb1, n8);

    // ---- CSR build ----
    const int Etot = E_a0 + E_a1 + E_i1 + E_i2;
    hipMemsetAsync(bins_all, 0, (size_t)4 * NCELLS * sizeof(int), stream);
    hist4_kernel<<<(Etot + 255) / 256, 256, 0, stream>>>(
        a0_recv, a1_recv, i1_recv, i2_recv, E_a0, E_a1, E_i1, E_i2, bins_all);
    scan_kernel<<<4, 1024, 0, stream>>>(bins_all, offs_all, NCELLS);
    hipMemsetAsync(bins_all, 0, (size_t)4 * NCELLS * sizeof(int), stream);
    rank4_kernel<<<(Etot + 255) / 256, 256, 0, stream>>>(
        a0_recv, a1_recv, i1_recv, i2_recv, E_a0, E_a1, E_i1, E_i2,
        offs_all, bins_all, pos0, pos1, pos2, pos3);

    const int* offs0 = offs_all;
    const int* offs1 = offs_all + (size_t)1 * (NCELLS + 1);
    const int* offs2 = offs_all + (size_t)2 * (NCELLS + 1);
    const int* offs3 = offs_all + (size_t)3 * (NCELLS + 1);

    float* out = (float*)d_out;
    const int UPD_BLK = (NCELLS + 63) / 64;

    // rank 0
    econv_kernel<3><<<(E_a0 + 63) / 64, 256, 0, stream>>>(
        fb0, fb0, a0_send, a0_recv, inv_a0,
        wb + o_w1[0], a0_b1, wb + o_w2[0], a0_b2, a0_Wg, a0_bg, pos0, msgA, E_a0);
    update_kernel<2><<<UPD_BLK, 256, 0, stream>>>(
        f0, fb0, msgA, offs0, nullptr, nullptr,
        wb + o_uw1[0], u0_b1, wb + o_uw2[0], u0_b2, out);

    // rank 1
    econv_kernel<6><<<(E_a1 + 63) / 64, 256, 0, stream>>>(
        fb1, fb1, a1_send, a1_recv, inv_a1,
        wb + o_w1[1], a1_b1, wb + o_w2[1], a1_b2, a1_Wg, a1_bg, pos1, msgA, E_a1);
    econv_kernel<3><<<(E_i1 + 63) / 64, 256, 0, stream>>>(
        fb0, fb1, i1_send, i1_recv, inv_i1,
        wb + o_w1[2], i1_b1, wb + o_w2[2], i1_b2, i1_Wg, i1_bg, pos2, msgB, E_i1);
    update_kernel<3><<<UPD_BLK, 256, 0, stream>>>(
        f1, fb1, msgA, offs1, msgB, offs2,
        wb + o_uw1[1], u1_b1, wb + o_uw2[1], u1_b2, out + (size_t)NCELLS * CDIM);

    // f2 -> bf16 (into msgB region, now dead)
    f2bf_kernel<<<CONV_BLK, 256, 0, stream>>>(f2, fb2, n8);

    // rank 2
    econv_kernel<6><<<(E_i2 + 63) / 64, 256, 0, stream>>>(
        fb1, fb2, i2_send, i2_recv, inv_i2,
        wb + o_w1[3], i2_b1, wb + o_w2[3], i2_b2, i2_Wg, i2_bg, pos3, msgA, E_i2);
    update_kernel<2><<<UPD_BLK, 256, 0, stream>>>(
        f2, fb2, msgA, offs3, nullptr, nullptr,
        wb + o_uw1[2], u2_b1, wb + o_uw2[2], u2_b2, out + 2 * (size_t)NCELLS * CDIM);
}